// Round 5
// baseline (612.666 us; speedup 1.0000x reference)
//
#include <hip/hip_runtime.h>
#include <hip/hip_bf16.h>
#include <stdint.h>

#define NA 500000
#define NB 500000
#define EE 1000000
#define NBUCK 3907          // ceil(500000/128)
// Per-XCD slice capacities. 8 slices per bucket.
#define SCAPA 88            // 8*88  = 704 entries/bucket
#define SCAPB 50            // 8*50  = 400 entries/bucket
#define OCAP 4096

__device__ __forceinline__ uint32_t f2bf(float f) {
    uint32_t b = __builtin_bit_cast(uint32_t, f);
    return (b + 0x7FFFu + ((b >> 16) & 1u)) >> 16;  // RNE
}

__device__ __forceinline__ int xcc_id() {
    int x;
    asm("s_getreg_b32 %0, hwreg(HW_REG_XCC_ID)" : "=s"(x));
    return x & 7;
}

// ---- K1: bucket scatter, XCD-sliced. entry = src | type<<19 | dstLocal<<20 ----
__global__ __launch_bounds__(256) void bucket_scatter(
    const int* __restrict__ ei_ab, const int* __restrict__ ei_ba,
    const int* __restrict__ ei_aa,
    int* __restrict__ cnt_a, int* __restrict__ cnt_b,
    uint32_t* __restrict__ buck_a, uint32_t* __restrict__ buck_b,
    int* __restrict__ ocnt, uint2* __restrict__ oflow) {
    const int xcd = xcc_id();
    int gid = blockIdx.x * 256 + threadIdx.x;
    if (gid >= 3 * EE) return;
    int dst, src, type, famA;
    if (gid < EE) {                 // ab -> dst is b-node, src indexes xa/ta0
        dst = ei_ab[EE + gid]; src = ei_ab[gid]; type = 0; famA = 0;
    } else if (gid < 2 * EE) {      // ba -> dst a-node, src indexes xb/tb1
        int e = gid - EE;
        dst = ei_ba[EE + e]; src = ei_ba[e]; type = 0; famA = 1;
    } else {                        // aa -> dst a-node, src indexes xa/ta2
        int e = gid - 2 * EE;
        dst = ei_aa[EE + e]; src = ei_aa[e]; type = 1; famA = 1;
    }
    int bucket = dst >> 7;
    uint32_t entry = (uint32_t)src | ((uint32_t)type << 19) |
                     ((uint32_t)(dst & 127) << 20);
    int cap = famA ? SCAPA : SCAPB;
    int* cnt = famA ? cnt_a : cnt_b;
    uint32_t* buck = famA ? buck_a : buck_b;
    int slot = atomicAdd(&cnt[xcd * NBUCK + bucket], 1);
    if (slot < cap) {
        buck[((size_t)bucket * 8 + xcd) * cap + slot] = entry;
    } else {
        bool placed = false;
        for (int d = 1; d < 8; ++d) {
            int s2 = (xcd + d) & 7;
            int sl2 = atomicAdd(&cnt[s2 * NBUCK + bucket], 1);
            if (sl2 < cap) {
                buck[((size_t)bucket * 8 + s2) * cap + sl2] = entry;
                placed = true;
                break;
            }
        }
        if (!placed) {
            int o = atomicAdd(ocnt, 1);
            if (o < OCAP)
                oflow[o] = make_uint2((uint32_t)dst | ((uint32_t)famA << 30) |
                                      ((uint32_t)type << 29), (uint32_t)src);
        }
    }
}

// ---- K2: per-bucket counting sort in LDS + layer-1 scalar aggregation ----
__global__ __launch_bounds__(256) void sort_agg(
    const int* __restrict__ cnt_a, const int* __restrict__ cnt_b,
    uint32_t* __restrict__ buck_a, uint32_t* __restrict__ buck_b,
    const float* __restrict__ xa, const float* __restrict__ xb,
    float* __restrict__ agg_ba, float* __restrict__ agg_aa,
    float* __restrict__ agg_ab,
    uint16_t* __restrict__ start16_a, uint16_t* __restrict__ start16_b,
    uint16_t* __restrict__ ktot_a, uint16_t* __restrict__ ktot_b) {
    __shared__ uint32_t raw[8 * SCAPA];
    __shared__ uint32_t sorted[8 * SCAPA];
    __shared__ int hist[128], cursor[128], startS[128], fillC[128];
    __shared__ int offS[9];
    __shared__ float sAgg[256];
    const int bucket = blockIdx.x;
    const int isA = (blockIdx.y == 0);
    const int cap = isA ? SCAPA : SCAPB;
    const int* cnt = isA ? cnt_a : cnt_b;
    uint32_t* buckbase = (isA ? buck_a : buck_b) + (size_t)bucket * 8 * cap;
    const int t = threadIdx.x;
    if (t < 128) hist[t] = 0;
    sAgg[t] = 0.f;
    if (t == 0) {
        int acc = 0;
        offS[0] = 0;
        for (int s = 0; s < 8; ++s) {
            int c = cnt[s * NBUCK + bucket];
            c = c < cap ? c : cap;
            acc += c;
            offS[s + 1] = acc;
        }
    }
    __syncthreads();
    const int K = offS[8];
    for (int i = t; i < K; i += 256) {
        int s = 0;
        while (i >= offS[s + 1]) ++s;         // <=8 LDS probes, no scratch
        uint32_t e = buckbase[s * cap + (i - offS[s])];
        raw[i] = e;
        atomicAdd(&hist[e >> 20], 1);
    }
    __syncthreads();
    // inclusive scan of hist -> cursor
    if (t < 128) cursor[t] = hist[t];
    __syncthreads();
    for (int off = 1; off < 128; off <<= 1) {
        int v = 0;
        if (t < 128) { v = cursor[t]; if (t >= off) v += cursor[t - off]; }
        __syncthreads();
        if (t < 128) cursor[t] = v;
        __syncthreads();
    }
    if (t < 128) {
        int st = cursor[t] - hist[t];   // exclusive
        startS[t] = st;
        fillC[t] = st;
    }
    __syncthreads();
    // place + aggregate
    for (int i = t; i < K; i += 256) {
        uint32_t e = raw[i];
        int loc = e >> 20;
        int type = (e >> 19) & 1;
        int src = e & 0x7FFFF;
        int pos = atomicAdd(&fillC[loc], 1);
        sorted[pos] = e;
        float xv = isA ? (type ? xa[src] : xb[src]) : xa[src];
        atomicAdd(&sAgg[loc * 2 + type], xv);
    }
    __syncthreads();
    // compact sorted entries to front of bucket region
    for (int i = t; i < K; i += 256) buckbase[i] = sorted[i];
    if (t == 0) {
        if (isA) ktot_a[bucket] = (uint16_t)K;
        else     ktot_b[bucket] = (uint16_t)K;
    }
    if (t < 128) {
        int n = bucket * 128 + t;
        if (isA) {
            start16_a[bucket * 128 + t] = (uint16_t)startS[t];
            if (n < NA) {
                agg_ba[n] = sAgg[t * 2];
                agg_aa[n] = sAgg[t * 2 + 1];
            }
        } else {
            start16_b[bucket * 128 + t] = (uint16_t)startS[t];
            if (n < NB) agg_ab[n] = sAgg[t * 2];
        }
    }
}

// ---- K2b: overflow agg fixup (normally ~zero iterations) ----
__global__ __launch_bounds__(256) void oflow_agg(
    const int* __restrict__ ocnt, const uint2* __restrict__ oflow,
    const float* __restrict__ xa, const float* __restrict__ xb,
    float* __restrict__ agg_ba, float* __restrict__ agg_aa,
    float* __restrict__ agg_ab) {
    int n = *ocnt;
    n = n < OCAP ? n : OCAP;
    for (int i = threadIdx.x; i < n; i += 256) {
        uint2 r = oflow[i];
        int dst = r.x & 0x1FFFFFFF;
        int famA = (r.x >> 30) & 1;
        int type = (r.x >> 29) & 1;
        int src = (int)r.y;
        if (famA) {
            if (type) atomicAdd(&agg_aa[dst], xa[src]);
            else      atomicAdd(&agg_ba[dst], xb[src]);
        } else {
            atomicAdd(&agg_ab[dst], xa[src]);
        }
    }
}

// ---- K5: overflow out fixup (after gather; normally ~zero iterations) ----
__global__ __launch_bounds__(256) void oflow_out(
    const int* __restrict__ ocnt, const uint2* __restrict__ oflow,
    const uint16_t* __restrict__ ta0, const uint16_t* __restrict__ ta2,
    const uint16_t* __restrict__ tb1,
    float* __restrict__ outa, float* __restrict__ outb) {
    int n = *ocnt;
    n = n < OCAP ? n : OCAP;
    for (int i = threadIdx.x; i < n; i += 256) {
        uint2 r = oflow[i];
        int dst = r.x & 0x1FFFFFFF;
        int famA = (r.x >> 30) & 1;
        int type = (r.x >> 29) & 1;
        int src = (int)r.y;
        const uint16_t* tp = famA ? (type ? ta2 : tb1) : ta0;
        float* out = famA ? outa : outb;
        for (int k = 0; k < 32; ++k) {
            float v = __builtin_bit_cast(float,
                          (uint32_t)tp[(size_t)src * 32 + k] << 16);
            atomicAdd(&out[(size_t)dst * 32 + k], v);
        }
    }
}

// ---- K4: gather, 8 lanes per dst node ----
__global__ __launch_bounds__(256) void gather_out(
    const uint16_t* __restrict__ ktot_a, const uint16_t* __restrict__ ktot_b,
    const uint16_t* __restrict__ start16_a, const uint16_t* __restrict__ start16_b,
    const uint32_t* __restrict__ buck_a, const uint32_t* __restrict__ buck_b,
    const uint16_t* __restrict__ ta0, const uint16_t* __restrict__ ta2,
    const uint16_t* __restrict__ tb1,
    float* __restrict__ outa, float* __restrict__ outb) {
    int gid = blockIdx.x * 256 + threadIdx.x;   // exactly (NA+NB)*8 threads
    int n3 = gid >> 3;
    int l = gid & 7;
    float4 acc = make_float4(0.f, 0.f, 0.f, 0.f);
    if (n3 < NA) {
        int bucket = n3 >> 7, local = n3 & 127;
        int start = start16_a[n3];
        int end;
        if (local == 127) end = ktot_a[bucket];
        else              end = start16_a[n3 + 1];
        const uint32_t* bp = buck_a + (size_t)bucket * (8 * SCAPA);
        for (int i = start; i < end; ++i) {
            uint32_t e = bp[i];
            int src = e & 0x7FFFF;
            const uint16_t* tp = (e & (1u << 19)) ? ta2 : tb1;
            uint2 u = *(const uint2*)(tp + (size_t)src * 32 + l * 4);
            acc.x += __builtin_bit_cast(float, u.x << 16);
            acc.y += __builtin_bit_cast(float, u.x & 0xFFFF0000u);
            acc.z += __builtin_bit_cast(float, u.y << 16);
            acc.w += __builtin_bit_cast(float, u.y & 0xFFFF0000u);
        }
        float4* po = (float4*)(outa + (size_t)n3 * 32 + l * 4);
        float4 cur = *po;
        *po = make_float4(cur.x + acc.x, cur.y + acc.y, cur.z + acc.z, cur.w + acc.w);
    } else {
        int n = n3 - NA;
        int bucket = n >> 7, local = n & 127;
        int start = start16_b[n];
        int end;
        if (local == 127) end = ktot_b[bucket];
        else              end = start16_b[n + 1];
        const uint32_t* bp = buck_b + (size_t)bucket * (8 * SCAPB);
        for (int i = start; i < end; ++i) {
            uint32_t e = bp[i];
            int src = e & 0x7FFFF;
            uint2 u = *(const uint2*)(ta0 + (size_t)src * 32 + l * 4);
            acc.x += __builtin_bit_cast(float, u.x << 16);
            acc.y += __builtin_bit_cast(float, u.x & 0xFFFF0000u);
            acc.z += __builtin_bit_cast(float, u.y << 16);
            acc.w += __builtin_bit_cast(float, u.y & 0xFFFF0000u);
        }
        float4* po = (float4*)(outb + (size_t)n * 32 + l * 4);
        float4 cur = *po;
        *po = make_float4(cur.x + acc.x, cur.y + acc.y, cur.z + acc.z, cur.w + acc.w);
    }
}

// ---- prep_weights: precompute fused weight combos into scratch (global) ----
// wpack layout (floats):
//   [0:2048)     WA2sum = Wroot2[2048+i] + Wroot2[4096+i]   (A pass-3 matrix)
//   [2048:2304)  uvwcA float4[64]: (Wrel1[64+j], Wrel1[128+j],
//                                   Wroot1[64+j]+Wroot1[128+j], b1[64+j]+b1[128+j])
//   [2304:2560)  uvwcB float4[64]: (Wrel1[j], 0, Wroot1[j], b1[j])
//   [2560:2592)  bbA[32] = b2[32+o] + b2[64+o]
//   [2592:2624)  bbB[32] = b2[o]
__global__ __launch_bounds__(256) void prep_weights(
    const float* __restrict__ Wrel1, const float* __restrict__ Wroot1,
    const float* __restrict__ b1,
    const float* __restrict__ Wroot2, const float* __restrict__ b2,
    float* __restrict__ wpack) {
    const int t = threadIdx.x;
    for (int i = t; i < 2048; i += 256)
        wpack[i] = Wroot2[2048 + i] + Wroot2[4096 + i];
    if (t < 64) {
        float4* uvA = (float4*)(wpack + 2048);
        float4* uvB = (float4*)(wpack + 2304);
        uvA[t] = make_float4(Wrel1[64 + t], Wrel1[128 + t],
                             Wroot1[64 + t] + Wroot1[128 + t],
                             b1[64 + t] + b1[128 + t]);
        uvB[t] = make_float4(Wrel1[t], 0.f, Wroot1[t], b1[t]);
    }
    if (t >= 64 && t < 96) {
        int o = t - 64;
        wpack[2560 + o] = b2[32 + o] + b2[64 + o];
        wpack[2592 + o] = b2[o];
    }
}

// One GEMM pass, 1 node/thread, SCALAR (SGPR) weights, acc in 32 VGPRs.
#define MM_PASS_S1(WP)                                                       \
    _Pragma("unroll 2")                                                      \
    for (int j = 0; j < 64; ++j) {                                           \
        float4 c4 = uv4[j];                                                  \
        float h = fmaxf(fmaf(in0, c4.x,                                      \
                     fmaf(in1, c4.y, fmaf(in2, c4.z, c4.w))), 0.f);          \
        const float* wrow = (WP) + j * 32;                                   \
        _Pragma("unroll")                                                    \
        for (int q = 0; q < 32; ++q)                                         \
            acc[q] = fmaf(h, wrow[q], acc[q]);                               \
    }

// Direct bf16 store: pack 32 accs to 16 u32 words, 4x uint4 per thread.
// Wave fills a contiguous 4KB span (full lines) -> coalesced at L2.
#define STORE_BF16(DSTPTR)                                                   \
    if (vld) {                                                               \
        uint4* dst_ = (uint4*)(DSTPTR) + (size_t)n * 4;                      \
        _Pragma("unroll")                                                    \
        for (int k = 0; k < 4; ++k)                                          \
            dst_[k] = make_uint4(                                            \
                f2bf(acc[8 * k + 0]) | (f2bf(acc[8 * k + 1]) << 16),         \
                f2bf(acc[8 * k + 2]) | (f2bf(acc[8 * k + 3]) << 16),         \
                f2bf(acc[8 * k + 4]) | (f2bf(acc[8 * k + 5]) << 16),         \
                f2bf(acc[8 * k + 6]) | (f2bf(acc[8 * k + 7]) << 16));        \
    }

#define STORE_F32(DSTPTR)                                                    \
    if (vld) {                                                               \
        float4* dst_ = (float4*)(DSTPTR) + (size_t)n * 8;                    \
        _Pragma("unroll")                                                    \
        for (int k = 0; k < 8; ++k)                                          \
            dst_[k] = make_float4(acc[4 * k + 0], acc[4 * k + 1],            \
                                  acc[4 * k + 2], acc[4 * k + 3]);           \
    }

// ============ merged node kernel: even blocks = A, odd blocks = B ==========
// 1 node/thread, zero LDS, zero barriers; weights via scalar path (SGPR).
__global__ __launch_bounds__(256) void node_ab_kernel(
    const float* __restrict__ xa, const float* __restrict__ xb,
    const float* __restrict__ s_ba, const float* __restrict__ s_aa,
    const float* __restrict__ s_ab,
    const float* __restrict__ Wrel2, const float* __restrict__ Wroot2,
    const float* __restrict__ wpack,
    uint16_t* __restrict__ ta0, uint16_t* __restrict__ ta2,
    uint16_t* __restrict__ tb1,
    float* __restrict__ outa, float* __restrict__ outb) {
    const int t = threadIdx.x;
    const bool isA = (blockIdx.x & 1) == 0;
    const int n = (blockIdx.x >> 1) * 256 + t;

    const float4* uv4 = (const float4*)(wpack + (isA ? 2048 : 2304));
    const float*  bb  = wpack + (isA ? 2560 : 2592);

    float in0, in1, in2;
    bool vld;
    if (isA) {
        vld = n < NA;
        in0 = vld ? s_ba[n] : 0.f;
        in1 = vld ? s_aa[n] : 0.f;
        in2 = vld ? xa[n]   : 0.f;
    } else {
        vld = n < NB;
        in0 = vld ? s_ab[n] : 0.f;
        in1 = 0.f;
        in2 = vld ? xb[n] : 0.f;
    }

    float acc[32];
    if (isA) {
        // pass 1: h*Wrel2[0] -> ta0 (bf16)
#pragma unroll
        for (int o = 0; o < 32; ++o) acc[o] = 0.f;
        MM_PASS_S1(Wrel2)
        STORE_BF16(ta0)

        // pass 2: h*Wrel2[2] -> ta2 (bf16)
#pragma unroll
        for (int o = 0; o < 32; ++o) acc[o] = 0.f;
        MM_PASS_S1(Wrel2 + 4096)
        STORE_BF16(ta2)

        // pass 3: h*(Wroot2[1]+Wroot2[2]) + bias -> outa (f32)
#pragma unroll
        for (int o = 0; o < 32; ++o) acc[o] = bb[o];
        MM_PASS_S1(wpack)
        STORE_F32(outa)
    } else {
        // pass 1: h*Wrel2[1] -> tb1 (bf16)
#pragma unroll
        for (int o = 0; o < 32; ++o) acc[o] = 0.f;
        MM_PASS_S1(Wrel2 + 2048)
        STORE_BF16(tb1)

        // pass 2: h*Wroot2[0] + bias -> outb (f32)
#pragma unroll
        for (int o = 0; o < 32; ++o) acc[o] = bb[o];
        MM_PASS_S1(Wroot2)
        STORE_F32(outb)
    }
}

extern "C" void kernel_launch(void* const* d_in, const int* in_sizes, int n_in,
                              void* d_out, int out_size, void* d_ws, size_t ws_size,
                              hipStream_t stream) {
    const float* x_a    = (const float*)d_in[0];
    const float* x_b    = (const float*)d_in[1];
    const int*   ei_ab  = (const int*)d_in[2];
    const int*   ei_ba  = (const int*)d_in[3];
    const int*   ei_aa  = (const int*)d_in[4];
    const float* Wrel1  = (const float*)d_in[5];
    const float* Wroot1 = (const float*)d_in[6];
    const float* b1     = (const float*)d_in[7];
    const float* Wrel2  = (const float*)d_in[8];
    const float* Wroot2 = (const float*)d_in[9];
    const float* b2     = (const float*)d_in[10];

    float* outa = (float*)d_out;                       // [NA,32]
    float* outb = (float*)d_out + (size_t)NA * 32;     // [NB,32]

    char* ws = (char*)d_ws;
    // Layout (bytes):
    uint32_t* buck_a   = (uint32_t*)(ws);                    // 3907*704*4  = 11,002,112
    uint32_t* buck_b   = (uint32_t*)(ws + 11002112);         // 3907*400*4  =  6,251,200
    float*    agg_ba   = (float*)(ws + 17253312);            // NA floats   =  2,000,000
    float*    agg_aa   = (float*)(ws + 19253312);            // NA floats
    float*    agg_ab   = (float*)(ws + 21253312);            // NB floats
    uint16_t* ta0      = (uint16_t*)(ws + 23253312);         // NA*32 bf16  = 32,000,000
    uint16_t* ta2      = (uint16_t*)(ws + 55253312);         // NA*32 bf16
    uint16_t* tb1      = (uint16_t*)(ws + 87253312);         // NB*32 bf16
    uint16_t* start16_a= (uint16_t*)(ws + 119253312);        // 3907*128 u16 = 1,000,192
    uint16_t* start16_b= (uint16_t*)(ws + 120253504);        // 3907*128 u16
    uint16_t* ktot_a   = (uint16_t*)(ws + 121253696);        // 3907 u16 (pad 8192)
    uint16_t* ktot_b   = (uint16_t*)(ws + 121261888);        // 3907 u16 (pad 8192)
    int*      cnt_a    = (int*)(ws + 121270080);             // 8*3907 int = 125,024
    int*      cnt_b    = (int*)(ws + 121395104);             // 8*3907 int
    int*      ocnt     = (int*)(ws + 121520128);             // 1 int (+4 pad)
    uint2*    oflow    = (uint2*)(ws + 121520136);           // 4096 uint2 = 32,768
    float*    wpack    = (float*)(ws + 121552960);           // 2624 floats = 10,496
    if (ws_size < 121600000) return;  // need ~121.6 MB scratch

    // zero cnt_a, cnt_b, ocnt (one contiguous span)
    hipMemsetAsync((char*)cnt_a, 0, 125024 + 125024 + 8, stream);

    dim3 blk(256);
    prep_weights<<<1, blk, 0, stream>>>(Wrel1, Wroot1, b1, Wroot2, b2, wpack);

    int egrid = (3 * EE + 255) / 256;
    bucket_scatter<<<egrid, blk, 0, stream>>>(ei_ab, ei_ba, ei_aa, cnt_a, cnt_b,
                                              buck_a, buck_b, ocnt, oflow);

    sort_agg<<<dim3(NBUCK, 2), blk, 0, stream>>>(cnt_a, cnt_b, buck_a, buck_b,
                                                 x_a, x_b, agg_ba, agg_aa, agg_ab,
                                                 start16_a, start16_b,
                                                 ktot_a, ktot_b);
    oflow_agg<<<1, blk, 0, stream>>>(ocnt, oflow, x_a, x_b, agg_ba, agg_aa, agg_ab);

    int ngrid_half = (NA + 255) / 256;   // 1954
    node_ab_kernel<<<2 * ngrid_half, blk, 0, stream>>>(
        x_a, x_b, agg_ba, agg_aa, agg_ab, Wrel2, Wroot2, wpack,
        ta0, ta2, tb1, outa, outb);

    int ggrid = (int)(((size_t)(NA + NB) * 8) / 256);  // 31250 exact
    gather_out<<<ggrid, blk, 0, stream>>>(ktot_a, ktot_b, start16_a, start16_b,
                                          buck_a, buck_b, ta0, ta2, tb1,
                                          outa, outb);
    oflow_out<<<1, blk, 0, stream>>>(ocnt, oflow, ta0, ta2, tb1, outa, outb);
}

// Round 6
// 559.547 us; speedup vs baseline: 1.0949x; 1.0949x over previous
//
#include <hip/hip_runtime.h>
#include <hip/hip_bf16.h>
#include <stdint.h>

#define NA 500000
#define NB 500000
#define EE 1000000
#define NBUCK 3907          // ceil(500000/128)
// Per-XCD slice capacities. 8 slices per bucket.
#define SCAPA 88            // 8*88  = 704 entries/bucket
#define SCAPB 50            // 8*50  = 400 entries/bucket
#define OCAP 4096

__device__ __forceinline__ uint32_t f2bf(float f) {
    uint32_t b = __builtin_bit_cast(uint32_t, f);
    return (b + 0x7FFFu + ((b >> 16) & 1u)) >> 16;  // RNE
}

__device__ __forceinline__ int xcc_id() {
    int x;
    asm("s_getreg_b32 %0, hwreg(HW_REG_XCC_ID)" : "=s"(x));
    return x & 7;
}

// ---- K1: bucket scatter, XCD-sliced. entry = src | type<<19 | dstLocal<<20 ----
__global__ __launch_bounds__(256) void bucket_scatter(
    const int* __restrict__ ei_ab, const int* __restrict__ ei_ba,
    const int* __restrict__ ei_aa,
    int* __restrict__ cnt_a, int* __restrict__ cnt_b,
    uint32_t* __restrict__ buck_a, uint32_t* __restrict__ buck_b,
    int* __restrict__ ocnt, uint2* __restrict__ oflow) {
    const int xcd = xcc_id();
    int gid = blockIdx.x * 256 + threadIdx.x;
    if (gid >= 3 * EE) return;
    int dst, src, type, famA;
    if (gid < EE) {                 // ab -> dst is b-node, src indexes xa/ta0
        dst = ei_ab[EE + gid]; src = ei_ab[gid]; type = 0; famA = 0;
    } else if (gid < 2 * EE) {      // ba -> dst a-node, src indexes xb/tb1
        int e = gid - EE;
        dst = ei_ba[EE + e]; src = ei_ba[e]; type = 0; famA = 1;
    } else {                        // aa -> dst a-node, src indexes xa/ta2
        int e = gid - 2 * EE;
        dst = ei_aa[EE + e]; src = ei_aa[e]; type = 1; famA = 1;
    }
    int bucket = dst >> 7;
    uint32_t entry = (uint32_t)src | ((uint32_t)type << 19) |
                     ((uint32_t)(dst & 127) << 20);
    int cap = famA ? SCAPA : SCAPB;
    int* cnt = famA ? cnt_a : cnt_b;
    uint32_t* buck = famA ? buck_a : buck_b;
    int slot = atomicAdd(&cnt[xcd * NBUCK + bucket], 1);
    if (slot < cap) {
        buck[((size_t)bucket * 8 + xcd) * cap + slot] = entry;
    } else {
        bool placed = false;
        for (int d = 1; d < 8; ++d) {
            int s2 = (xcd + d) & 7;
            int sl2 = atomicAdd(&cnt[s2 * NBUCK + bucket], 1);
            if (sl2 < cap) {
                buck[((size_t)bucket * 8 + s2) * cap + sl2] = entry;
                placed = true;
                break;
            }
        }
        if (!placed) {
            int o = atomicAdd(ocnt, 1);
            if (o < OCAP)
                oflow[o] = make_uint2((uint32_t)dst | ((uint32_t)famA << 30) |
                                      ((uint32_t)type << 29), (uint32_t)src);
        }
    }
}

// ---- K2: per-bucket counting sort in LDS + layer-1 scalar aggregation ----
__global__ __launch_bounds__(256) void sort_agg(
    const int* __restrict__ cnt_a, const int* __restrict__ cnt_b,
    uint32_t* __restrict__ buck_a, uint32_t* __restrict__ buck_b,
    const float* __restrict__ xa, const float* __restrict__ xb,
    float* __restrict__ agg_ba, float* __restrict__ agg_aa,
    float* __restrict__ agg_ab,
    uint16_t* __restrict__ start16_a, uint16_t* __restrict__ start16_b,
    uint16_t* __restrict__ ktot_a, uint16_t* __restrict__ ktot_b) {
    __shared__ uint32_t raw[8 * SCAPA];
    __shared__ uint32_t sorted[8 * SCAPA];
    __shared__ int hist[128], cursor[128], startS[128], fillC[128];
    __shared__ int offS[9];
    __shared__ float sAgg[256];
    const int bucket = blockIdx.x;
    const int isA = (blockIdx.y == 0);
    const int cap = isA ? SCAPA : SCAPB;
    const int* cnt = isA ? cnt_a : cnt_b;
    uint32_t* buckbase = (isA ? buck_a : buck_b) + (size_t)bucket * 8 * cap;
    const int t = threadIdx.x;
    if (t < 128) hist[t] = 0;
    sAgg[t] = 0.f;
    if (t == 0) {
        int acc = 0;
        offS[0] = 0;
        for (int s = 0; s < 8; ++s) {
            int c = cnt[s * NBUCK + bucket];
            c = c < cap ? c : cap;
            acc += c;
            offS[s + 1] = acc;
        }
    }
    __syncthreads();
    const int K = offS[8];
    for (int i = t; i < K; i += 256) {
        int s = 0;
        while (i >= offS[s + 1]) ++s;         // <=8 LDS probes, no scratch
        uint32_t e = buckbase[s * cap + (i - offS[s])];
        raw[i] = e;
        atomicAdd(&hist[e >> 20], 1);
    }
    __syncthreads();
    // inclusive scan of hist -> cursor
    if (t < 128) cursor[t] = hist[t];
    __syncthreads();
    for (int off = 1; off < 128; off <<= 1) {
        int v = 0;
        if (t < 128) { v = cursor[t]; if (t >= off) v += cursor[t - off]; }
        __syncthreads();
        if (t < 128) cursor[t] = v;
        __syncthreads();
    }
    if (t < 128) {
        int st = cursor[t] - hist[t];   // exclusive
        startS[t] = st;
        fillC[t] = st;
    }
    __syncthreads();
    // place + aggregate
    for (int i = t; i < K; i += 256) {
        uint32_t e = raw[i];
        int loc = e >> 20;
        int type = (e >> 19) & 1;
        int src = e & 0x7FFFF;
        int pos = atomicAdd(&fillC[loc], 1);
        sorted[pos] = e;
        float xv = isA ? (type ? xa[src] : xb[src]) : xa[src];
        atomicAdd(&sAgg[loc * 2 + type], xv);
    }
    __syncthreads();
    // compact sorted entries to front of bucket region
    for (int i = t; i < K; i += 256) buckbase[i] = sorted[i];
    if (t == 0) {
        if (isA) ktot_a[bucket] = (uint16_t)K;
        else     ktot_b[bucket] = (uint16_t)K;
    }
    if (t < 128) {
        int n = bucket * 128 + t;
        if (isA) {
            start16_a[bucket * 128 + t] = (uint16_t)startS[t];
            if (n < NA) {
                agg_ba[n] = sAgg[t * 2];
                agg_aa[n] = sAgg[t * 2 + 1];
            }
        } else {
            start16_b[bucket * 128 + t] = (uint16_t)startS[t];
            if (n < NB) agg_ab[n] = sAgg[t * 2];
        }
    }
}

// ---- K2b: overflow agg fixup (normally ~zero iterations) ----
__global__ __launch_bounds__(256) void oflow_agg(
    const int* __restrict__ ocnt, const uint2* __restrict__ oflow,
    const float* __restrict__ xa, const float* __restrict__ xb,
    float* __restrict__ agg_ba, float* __restrict__ agg_aa,
    float* __restrict__ agg_ab) {
    int n = *ocnt;
    n = n < OCAP ? n : OCAP;
    for (int i = threadIdx.x; i < n; i += 256) {
        uint2 r = oflow[i];
        int dst = r.x & 0x1FFFFFFF;
        int famA = (r.x >> 30) & 1;
        int type = (r.x >> 29) & 1;
        int src = (int)r.y;
        if (famA) {
            if (type) atomicAdd(&agg_aa[dst], xa[src]);
            else      atomicAdd(&agg_ba[dst], xb[src]);
        } else {
            atomicAdd(&agg_ab[dst], xa[src]);
        }
    }
}

// ---- K5: overflow out fixup (after gather; normally ~zero iterations) ----
__global__ __launch_bounds__(256) void oflow_out(
    const int* __restrict__ ocnt, const uint2* __restrict__ oflow,
    const uint16_t* __restrict__ ta0, const uint16_t* __restrict__ ta2,
    const uint16_t* __restrict__ tb1,
    float* __restrict__ outa, float* __restrict__ outb) {
    int n = *ocnt;
    n = n < OCAP ? n : OCAP;
    for (int i = threadIdx.x; i < n; i += 256) {
        uint2 r = oflow[i];
        int dst = r.x & 0x1FFFFFFF;
        int famA = (r.x >> 30) & 1;
        int type = (r.x >> 29) & 1;
        int src = (int)r.y;
        const uint16_t* tp = famA ? (type ? ta2 : tb1) : ta0;
        float* out = famA ? outa : outb;
        for (int k = 0; k < 32; ++k) {
            float v = __builtin_bit_cast(float,
                          (uint32_t)tp[(size_t)src * 32 + k] << 16);
            atomicAdd(&out[(size_t)dst * 32 + k], v);
        }
    }
}

// ---- K4: gather, 8 lanes per dst node ----
__global__ __launch_bounds__(256) void gather_out(
    const uint16_t* __restrict__ ktot_a, const uint16_t* __restrict__ ktot_b,
    const uint16_t* __restrict__ start16_a, const uint16_t* __restrict__ start16_b,
    const uint32_t* __restrict__ buck_a, const uint32_t* __restrict__ buck_b,
    const uint16_t* __restrict__ ta0, const uint16_t* __restrict__ ta2,
    const uint16_t* __restrict__ tb1,
    float* __restrict__ outa, float* __restrict__ outb) {
    int gid = blockIdx.x * 256 + threadIdx.x;   // exactly (NA+NB)*8 threads
    int n3 = gid >> 3;
    int l = gid & 7;
    float4 acc = make_float4(0.f, 0.f, 0.f, 0.f);
    if (n3 < NA) {
        int bucket = n3 >> 7, local = n3 & 127;
        int start = start16_a[n3];
        int end;
        if (local == 127) end = ktot_a[bucket];
        else              end = start16_a[n3 + 1];
        const uint32_t* bp = buck_a + (size_t)bucket * (8 * SCAPA);
        for (int i = start; i < end; ++i) {
            uint32_t e = bp[i];
            int src = e & 0x7FFFF;
            const uint16_t* tp = (e & (1u << 19)) ? ta2 : tb1;
            uint2 u = *(const uint2*)(tp + (size_t)src * 32 + l * 4);
            acc.x += __builtin_bit_cast(float, u.x << 16);
            acc.y += __builtin_bit_cast(float, u.x & 0xFFFF0000u);
            acc.z += __builtin_bit_cast(float, u.y << 16);
            acc.w += __builtin_bit_cast(float, u.y & 0xFFFF0000u);
        }
        float4* po = (float4*)(outa + (size_t)n3 * 32 + l * 4);
        float4 cur = *po;
        *po = make_float4(cur.x + acc.x, cur.y + acc.y, cur.z + acc.z, cur.w + acc.w);
    } else {
        int n = n3 - NA;
        int bucket = n >> 7, local = n & 127;
        int start = start16_b[n];
        int end;
        if (local == 127) end = ktot_b[bucket];
        else              end = start16_b[n + 1];
        const uint32_t* bp = buck_b + (size_t)bucket * (8 * SCAPB);
        for (int i = start; i < end; ++i) {
            uint32_t e = bp[i];
            int src = e & 0x7FFFF;
            uint2 u = *(const uint2*)(ta0 + (size_t)src * 32 + l * 4);
            acc.x += __builtin_bit_cast(float, u.x << 16);
            acc.y += __builtin_bit_cast(float, u.x & 0xFFFF0000u);
            acc.z += __builtin_bit_cast(float, u.y << 16);
            acc.w += __builtin_bit_cast(float, u.y & 0xFFFF0000u);
        }
        float4* po = (float4*)(outb + (size_t)n * 32 + l * 4);
        float4 cur = *po;
        *po = make_float4(cur.x + acc.x, cur.y + acc.y, cur.z + acc.z, cur.w + acc.w);
    }
}

// ---- prep_weights: precompute fused weight combos into scratch (global) ----
// wpack layout (floats):
//   [0:2048)     WA2sum = Wroot2[2048+i] + Wroot2[4096+i]   (A pass-3 matrix)
//   [2048:2304)  uvwcA float4[64]: (Wrel1[64+j], Wrel1[128+j],
//                                   Wroot1[64+j]+Wroot1[128+j], b1[64+j]+b1[128+j])
//   [2304:2560)  uvwcB float4[64]: (Wrel1[j], 0, Wroot1[j], b1[j])
//   [2560:2592)  bbA[32] = b2[32+o] + b2[64+o]
//   [2592:2624)  bbB[32] = b2[o]
__global__ __launch_bounds__(256) void prep_weights(
    const float* __restrict__ Wrel1, const float* __restrict__ Wroot1,
    const float* __restrict__ b1,
    const float* __restrict__ Wroot2, const float* __restrict__ b2,
    float* __restrict__ wpack) {
    const int t = threadIdx.x;
    for (int i = t; i < 2048; i += 256)
        wpack[i] = Wroot2[2048 + i] + Wroot2[4096 + i];
    if (t < 64) {
        float4* uvA = (float4*)(wpack + 2048);
        float4* uvB = (float4*)(wpack + 2304);
        uvA[t] = make_float4(Wrel1[64 + t], Wrel1[128 + t],
                             Wroot1[64 + t] + Wroot1[128 + t],
                             b1[64 + t] + b1[128 + t]);
        uvB[t] = make_float4(Wrel1[t], 0.f, Wroot1[t], b1[t]);
    }
    if (t >= 64 && t < 96) {
        int o = t - 64;
        wpack[2560 + o] = b2[32 + o] + b2[64 + o];
        wpack[2592 + o] = b2[o];
    }
}

// One GEMM pass, 2 nodes/thread, SCALAR (SGPR) weights.
// Each 128B s_load'd W row feeds 64 fmacs (~128 VALU cycles) -> covers
// the s_load latency that bound R5's NPT=1 variant.
#define MM_PASS_S2(WP)                                                       \
    _Pragma("unroll 2")                                                      \
    for (int j = 0; j < 64; ++j) {                                           \
        float4 c4 = uv4[j];                                                  \
        float h0 = fmaxf(fmaf(in0[0], c4.x,                                  \
                     fmaf(in1[0], c4.y, fmaf(in2[0], c4.z, c4.w))), 0.f);    \
        float h1 = fmaxf(fmaf(in0[1], c4.x,                                  \
                     fmaf(in1[1], c4.y, fmaf(in2[1], c4.z, c4.w))), 0.f);    \
        const float* wrow = (WP) + j * 32;                                   \
        _Pragma("unroll")                                                    \
        for (int q = 0; q < 32; ++q) {                                       \
            float w = wrow[q];                                               \
            acc0[q] = fmaf(h0, w, acc0[q]);                                  \
            acc1[q] = fmaf(h1, w, acc1[q]);                                  \
        }                                                                    \
    }

// Direct bf16 store of both nodes: 4x uint4 each, contiguous per wave.
#define STORE_BF16_2(DSTPTR)                                                 \
    {                                                                        \
        if (v0) {                                                            \
            uint4* d_ = (uint4*)(DSTPTR) + (size_t)n0 * 4;                   \
            _Pragma("unroll")                                                \
            for (int k = 0; k < 4; ++k)                                      \
                d_[k] = make_uint4(                                          \
                    f2bf(acc0[8 * k + 0]) | (f2bf(acc0[8 * k + 1]) << 16),   \
                    f2bf(acc0[8 * k + 2]) | (f2bf(acc0[8 * k + 3]) << 16),   \
                    f2bf(acc0[8 * k + 4]) | (f2bf(acc0[8 * k + 5]) << 16),   \
                    f2bf(acc0[8 * k + 6]) | (f2bf(acc0[8 * k + 7]) << 16));  \
        }                                                                    \
        if (v1) {                                                            \
            uint4* d_ = (uint4*)(DSTPTR) + (size_t)n1 * 4;                   \
            _Pragma("unroll")                                                \
            for (int k = 0; k < 4; ++k)                                      \
                d_[k] = make_uint4(                                          \
                    f2bf(acc1[8 * k + 0]) | (f2bf(acc1[8 * k + 1]) << 16),   \
                    f2bf(acc1[8 * k + 2]) | (f2bf(acc1[8 * k + 3]) << 16),   \
                    f2bf(acc1[8 * k + 4]) | (f2bf(acc1[8 * k + 5]) << 16),   \
                    f2bf(acc1[8 * k + 6]) | (f2bf(acc1[8 * k + 7]) << 16));  \
        }                                                                    \
    }

#define STORE_F32_2(DSTPTR)                                                  \
    {                                                                        \
        if (v0) {                                                            \
            float4* d_ = (float4*)(DSTPTR) + (size_t)n0 * 8;                 \
            _Pragma("unroll")                                                \
            for (int k = 0; k < 8; ++k)                                      \
                d_[k] = make_float4(acc0[4 * k + 0], acc0[4 * k + 1],        \
                                    acc0[4 * k + 2], acc0[4 * k + 3]);       \
        }                                                                    \
        if (v1) {                                                            \
            float4* d_ = (float4*)(DSTPTR) + (size_t)n1 * 8;                 \
            _Pragma("unroll")                                                \
            for (int k = 0; k < 8; ++k)                                      \
                d_[k] = make_float4(acc1[4 * k + 0], acc1[4 * k + 1],        \
                                    acc1[4 * k + 2], acc1[4 * k + 3]);       \
        }                                                                    \
    }

// ============ merged node kernel: even blocks = A, odd blocks = B ==========
// 2 nodes/thread, zero LDS, zero barriers; weights via scalar path (SGPR).
__global__ __launch_bounds__(256) void node_ab_kernel(
    const float* __restrict__ xa, const float* __restrict__ xb,
    const float* __restrict__ s_ba, const float* __restrict__ s_aa,
    const float* __restrict__ s_ab,
    const float* __restrict__ Wrel2, const float* __restrict__ Wroot2,
    const float* __restrict__ wpack,
    uint16_t* __restrict__ ta0, uint16_t* __restrict__ ta2,
    uint16_t* __restrict__ tb1,
    float* __restrict__ outa, float* __restrict__ outb) {
    const int t = threadIdx.x;
    const bool isA = (blockIdx.x & 1) == 0;
    const int base = (blockIdx.x >> 1) * 512;
    const int n0 = base + t;
    const int n1 = base + 256 + t;

    const float4* uv4 = (const float4*)(wpack + (isA ? 2048 : 2304));
    const float*  bb  = wpack + (isA ? 2560 : 2592);

    float in0[2], in1[2], in2[2];
    bool v0, v1;
    if (isA) {
        v0 = n0 < NA; v1 = n1 < NA;
        in0[0] = v0 ? s_ba[n0] : 0.f;  in0[1] = v1 ? s_ba[n1] : 0.f;
        in1[0] = v0 ? s_aa[n0] : 0.f;  in1[1] = v1 ? s_aa[n1] : 0.f;
        in2[0] = v0 ? xa[n0]   : 0.f;  in2[1] = v1 ? xa[n1]   : 0.f;
    } else {
        v0 = n0 < NB; v1 = n1 < NB;
        in0[0] = v0 ? s_ab[n0] : 0.f;  in0[1] = v1 ? s_ab[n1] : 0.f;
        in1[0] = 0.f;                  in1[1] = 0.f;
        in2[0] = v0 ? xb[n0]   : 0.f;  in2[1] = v1 ? xb[n1]   : 0.f;
    }

    float acc0[32], acc1[32];
    if (isA) {
        // pass 1: h*Wrel2[0] -> ta0 (bf16)
#pragma unroll
        for (int o = 0; o < 32; ++o) { acc0[o] = 0.f; acc1[o] = 0.f; }
        MM_PASS_S2(Wrel2)
        STORE_BF16_2(ta0)

        // pass 2: h*Wrel2[2] -> ta2 (bf16)
#pragma unroll
        for (int o = 0; o < 32; ++o) { acc0[o] = 0.f; acc1[o] = 0.f; }
        MM_PASS_S2(Wrel2 + 4096)
        STORE_BF16_2(ta2)

        // pass 3: h*(Wroot2[1]+Wroot2[2]) + bias -> outa (f32)
#pragma unroll
        for (int o = 0; o < 32; ++o) { acc0[o] = bb[o]; acc1[o] = bb[o]; }
        MM_PASS_S2(wpack)
        STORE_F32_2(outa)
    } else {
        // pass 1: h*Wrel2[1] -> tb1 (bf16)
#pragma unroll
        for (int o = 0; o < 32; ++o) { acc0[o] = 0.f; acc1[o] = 0.f; }
        MM_PASS_S2(Wrel2 + 2048)
        STORE_BF16_2(tb1)

        // pass 2: h*Wroot2[0] + bias -> outb (f32)
#pragma unroll
        for (int o = 0; o < 32; ++o) { acc0[o] = bb[o]; acc1[o] = bb[o]; }
        MM_PASS_S2(Wroot2)
        STORE_F32_2(outb)
    }
}

extern "C" void kernel_launch(void* const* d_in, const int* in_sizes, int n_in,
                              void* d_out, int out_size, void* d_ws, size_t ws_size,
                              hipStream_t stream) {
    const float* x_a    = (const float*)d_in[0];
    const float* x_b    = (const float*)d_in[1];
    const int*   ei_ab  = (const int*)d_in[2];
    const int*   ei_ba  = (const int*)d_in[3];
    const int*   ei_aa  = (const int*)d_in[4];
    const float* Wrel1  = (const float*)d_in[5];
    const float* Wroot1 = (const float*)d_in[6];
    const float* b1     = (const float*)d_in[7];
    const float* Wrel2  = (const float*)d_in[8];
    const float* Wroot2 = (const float*)d_in[9];
    const float* b2     = (const float*)d_in[10];

    float* outa = (float*)d_out;                       // [NA,32]
    float* outb = (float*)d_out + (size_t)NA * 32;     // [NB,32]

    char* ws = (char*)d_ws;
    // Layout (bytes):
    uint32_t* buck_a   = (uint32_t*)(ws);                    // 3907*704*4  = 11,002,112
    uint32_t* buck_b   = (uint32_t*)(ws + 11002112);         // 3907*400*4  =  6,251,200
    float*    agg_ba   = (float*)(ws + 17253312);            // NA floats   =  2,000,000
    float*    agg_aa   = (float*)(ws + 19253312);            // NA floats
    float*    agg_ab   = (float*)(ws + 21253312);            // NB floats
    uint16_t* ta0      = (uint16_t*)(ws + 23253312);         // NA*32 bf16  = 32,000,000
    uint16_t* ta2      = (uint16_t*)(ws + 55253312);         // NA*32 bf16
    uint16_t* tb1      = (uint16_t*)(ws + 87253312);         // NB*32 bf16
    uint16_t* start16_a= (uint16_t*)(ws + 119253312);        // 3907*128 u16 = 1,000,192
    uint16_t* start16_b= (uint16_t*)(ws + 120253504);        // 3907*128 u16
    uint16_t* ktot_a   = (uint16_t*)(ws + 121253696);        // 3907 u16 (pad 8192)
    uint16_t* ktot_b   = (uint16_t*)(ws + 121261888);        // 3907 u16 (pad 8192)
    int*      cnt_a    = (int*)(ws + 121270080);             // 8*3907 int = 125,024
    int*      cnt_b    = (int*)(ws + 121395104);             // 8*3907 int
    int*      ocnt     = (int*)(ws + 121520128);             // 1 int (+4 pad)
    uint2*    oflow    = (uint2*)(ws + 121520136);           // 4096 uint2 = 32,768
    float*    wpack    = (float*)(ws + 121552960);           // 2624 floats = 10,496
    if (ws_size < 121600000) return;  // need ~121.6 MB scratch

    // zero cnt_a, cnt_b, ocnt (one contiguous span)
    hipMemsetAsync((char*)cnt_a, 0, 125024 + 125024 + 8, stream);

    dim3 blk(256);
    prep_weights<<<1, blk, 0, stream>>>(Wrel1, Wroot1, b1, Wroot2, b2, wpack);

    int egrid = (3 * EE + 255) / 256;
    bucket_scatter<<<egrid, blk, 0, stream>>>(ei_ab, ei_ba, ei_aa, cnt_a, cnt_b,
                                              buck_a, buck_b, ocnt, oflow);

    sort_agg<<<dim3(NBUCK, 2), blk, 0, stream>>>(cnt_a, cnt_b, buck_a, buck_b,
                                                 x_a, x_b, agg_ba, agg_aa, agg_ab,
                                                 start16_a, start16_b,
                                                 ktot_a, ktot_b);
    oflow_agg<<<1, blk, 0, stream>>>(ocnt, oflow, x_a, x_b, agg_ba, agg_aa, agg_ab);

    int ngrid_half = (NA + 511) / 512;   // 977
    node_ab_kernel<<<2 * ngrid_half, blk, 0, stream>>>(
        x_a, x_b, agg_ba, agg_aa, agg_ab, Wrel2, Wroot2, wpack,
        ta0, ta2, tb1, outa, outb);

    int ggrid = (int)(((size_t)(NA + NB) * 8) / 256);  // 31250 exact
    gather_out<<<ggrid, blk, 0, stream>>>(ktot_a, ktot_b, start16_a, start16_b,
                                          buck_a, buck_b, ta0, ta2, tb1,
                                          outa, outb);
    oflow_out<<<1, blk, 0, stream>>>(ocnt, oflow, ta0, ta2, tb1, outa, outb);
}